// Round 9
// baseline (153.285 us; speedup 1.0000x reference)
//
#include <hip/hip_runtime.h>
#include <hip/hip_bf16.h>
#include <math.h>

// Problem constants (fixed by reference setup_inputs)
constexpr int NROWS = 8192;   // B
constexpr int HDIM  = 256;    // H (= K of the GEMM); also bytes/row in fp8
constexpr int N2    = 16384;  // 2*B rows of Z
constexpr int TM    = 256;    // tile M = tile N; 16 waves of 64x64 out each
constexpr int BKB   = 64;     // K per chunk (fp8: 64 k = 64 B/row staged)
constexpr int NCHUNK = HDIM / BKB;    // 4
constexpr int PIECEB = TM * BKB;      // 16 KB per piece (bytes)
constexpr int NTILE = N2 / TM;        // 64 tile-rows
constexpr int NBLK  = NTILE * (NTILE + 1) / 2;  // 2080 upper-tri tiles

// sqrt(2 * log2(e)): Z pre-scaled so Zs_i.Zs_j = 2*log2(e)*cos and
// exp2(acc) == exp(sim/tau), tau = 0.5
constexpr float PRESCALE = 1.69864357f;

typedef __attribute__((ext_vector_type(4))) float floatx4;

__device__ __forceinline__ void async_copy16(const void* gptr, void* lptr) {
    __builtin_amdgcn_global_load_lds(
        (const __attribute__((address_space(1))) unsigned int*)gptr,
        (__attribute__((address_space(3))) unsigned int*)lptr, 16, 0, 0);
}

// s_waitcnt immediates (gfx9: vm[3:0], exp[6:4], lgkm[11:8], vm-hi[15:14])
#define WAIT_VM2()   __builtin_amdgcn_s_waitcnt(0x0F72)  // vmcnt(2)
#define WAIT_VM0()   __builtin_amdgcn_s_waitcnt(0x0F70)  // vmcnt(0)
#define MEMFENCE()   __asm__ __volatile__("" ::: "memory")
#define RAW_BARRIER() do { MEMFENCE(); __builtin_amdgcn_s_barrier(); MEMFENCE(); } while (0)

// DPP row_shl add: VALU pipe, not DS (R9: -18us vs ds_bpermute shuffles).
#define DPP_ROW_SHL_ADD(v, CTRL) do {                                        \
    union { float f; int i; } _u, _r; _u.f = (v);                            \
    _r.i = __builtin_amdgcn_update_dpp(0, _u.i, (CTRL), 0xF, 0xF, true);     \
    (v) += _r.f; } while (0)

// Manual RNE float -> OCP e4m3fn (1-4-3, bias 7, subnormals m*2^-9).
// Inputs here are |v| <~ 1.7 so no overflow path needed beyond clamp.
__device__ __forceinline__ unsigned int f32_to_e4m3(float f) {
    const float a = fabsf(f);
    const unsigned int s = f < 0.f ? 0x80u : 0u;
    if (a < 0.015625f) {                       // subnormal: m = rne(a*512)
        int mm = (int)rintf(a * 512.0f);       // 0..8
        if (mm == 8) return s | 0x08u;         // rounds up to 2^-6
        return s | (unsigned int)mm;
    }
    int e; const float fr = frexpf(a, &e);     // a = fr*2^e, fr in [0.5,1)
    int mm = (int)rintf(fr * 16.0f) - 8;       // 0..8
    int E  = e + 6;                            // biased exponent
    if (mm == 8) { mm = 0; E += 1; }
    if (E > 15) { E = 15; mm = 6; }            // clamp to 448 (never hit)
    return s | (unsigned int)((E << 3) | mm);
}

// ---------------------------------------------------------------------------
// Kernel 1: wave-per-row L2-normalize -> FP8 e4m3 Z (pre-scaled);
// pos = cos(x,y) in exact fp32. Also zeroes rowsum and out.
// ---------------------------------------------------------------------------
__global__ __launch_bounds__(256) void normalize_kernel(
    const float* __restrict__ x, const float* __restrict__ y,
    unsigned char* __restrict__ Zb, float* __restrict__ pos,
    float* __restrict__ rowsum, float* __restrict__ out)
{
    const int wave = threadIdx.x >> 6, lane = threadIdx.x & 63;
    const int row  = blockIdx.x * 4 + wave;           // grid 2048 -> 8192 rows

    const float4 xv = ((const float4*)x)[row * 64 + lane];
    const float4 yv = ((const float4*)y)[row * 64 + lane];

    float sx  = xv.x*xv.x + xv.y*xv.y + xv.z*xv.z + xv.w*xv.w;
    float sy  = yv.x*yv.x + yv.y*yv.y + yv.z*yv.z + yv.w*yv.w;
    float sxy = xv.x*yv.x + xv.y*yv.y + xv.z*yv.z + xv.w*yv.w;
    #pragma unroll
    for (int m = 1; m < 64; m <<= 1) {
        sx  += __shfl_xor(sx,  m);
        sy  += __shfl_xor(sy,  m);
        sxy += __shfl_xor(sxy, m);
    }
    const float rxn = rsqrtf(sx), ryn = rsqrtf(sy);
    const float rx = rxn * PRESCALE, ry = ryn * PRESCALE;

    const unsigned int px =
        f32_to_e4m3(xv.x * rx)        | (f32_to_e4m3(xv.y * rx) << 8) |
        (f32_to_e4m3(xv.z * rx) << 16) | (f32_to_e4m3(xv.w * rx) << 24);
    const unsigned int py =
        f32_to_e4m3(yv.x * ry)        | (f32_to_e4m3(yv.y * ry) << 8) |
        (f32_to_e4m3(yv.z * ry) << 16) | (f32_to_e4m3(yv.w * ry) << 24);

    ((unsigned int*)Zb)[row * 64 + lane]             = px;  // 4 B/lane
    ((unsigned int*)Zb)[(row + NROWS) * 64 + lane]   = py;

    if (lane == 0) {
        const float p = sxy * rxn * ryn;   // exact fp32 numerator path
        pos[row]         = p;
        pos[row + NROWS] = p;
    }
    const int gt = blockIdx.x * 256 + threadIdx.x;
    if (gt < N2) rowsum[gt] = 0.f;
    if (gt == 0) out[0] = 0.f;
}

// ---------------------------------------------------------------------------
// Kernel 2: upper-triangle tiled Z·Z^T (FP8), fused exp2 + row/col sums.
// R17: fp8 e4m3 engine, BK=64 -> 4 chunks. After R10-R16 exonerated tile
// size, phase structure, prefetch depth, occupancy, and read/MFMA order
// (ten variants, all ~3650 cyc/chunk vs 1024 MFMA cyc), the remaining
// suspects are all byte- or chunk-proportional. fp8 halves ALL of them at
// unchanged MFMA work: staged bytes 532->266 MB, LDS frag bytes halved,
// chunks 8->4, Z 8->4 MB (fits one XCD L2).
// Layout: LDS byte-layout IDENTICAL to proven bf16 scheme (64 B/row, 4x16B
// slots/row, staging src-slot XOR (l&3)^((l>>3)&3)); fragment reads are
// b64: src 16B-slot s = ks*2+(g>>1), LDS slot = s ^ ((m15>>1)&3), +8B half
// (g&1). ~4-way bank aliasing accepted (path at ~16% util).
// Correctness: A and B frags use the SAME buffer and SAME per-lane
// k-window formula, so any intra-lane k-permutation cancels in the dot.
// Schedule = R16's proven 3-buffer 1-barrier-per-chunk:
//   body s: if s+1<4 {STAGE(s+1); vmcnt(2)} else vmcnt(0); BARRIER;
//           ds_read (16x b64); 32 MFMA (2 ksteps x 4x4).
// WAR/RAW arguments unchanged from R16 (3 buffers, stage-before-barrier).
// ---------------------------------------------------------------------------
__global__ __launch_bounds__(1024, 4) void simgemm_kernel(
    const unsigned char* __restrict__ Zb, float* __restrict__ rowsum)
{
    // ---- XCD-local block -> (bi,bj) mapping (bijection onto upper tri) ----
    const int b = blockIdx.x;
    const int k = b & 7;        // XCD under round-robin dispatch heuristic
    const int m = b >> 3;       // 0..259 local rank within XCD
    int bi, bj;
    if (m < 36) {
        int ti = (int)((17.0f - sqrtf(289.0f - 8.0f * (float)m)) * 0.5f);
        if (m < ti * (17 - ti) / 2) ti--;
        else if (m >= (ti + 1) * (16 - ti) / 2) ti++;
        const int tj = ti + (m - ti * (17 - ti) / 2);
        bi = k * 8 + ti;
        bj = k * 8 + tj;
    } else {
        const int m2 = m - 36;           // 0..223
        const int hh = m2 >> 5;          // 0..6
        const int r  = m2 & 31;          // 0..31
        const int h  = hh * 8 + k;       // 0..55
        const int q  = h >> 1;           // 0..27
        const int sub = h & 1;
        int gi = 0;
        #pragma unroll
        for (int t = 6; t > 0; --t)
            if (q >= t * (15 - t) / 2) { gi = t; break; }
        const int gj = gi + 1 + (q - gi * (15 - gi) / 2);
        bi = gi * 8 + sub * 4 + (r >> 3);
        bj = gj * 8 + (r & 7);
    }
    const bool diag = (bi == bj);

    // LDS: 3 buffers x (tA 16KB + tB 16KB) = 96KB, + rs/cs 2KB = 98KB
    __shared__ alignas(16) char tiles[6 * PIECEB];  // 96 KB
    __shared__ float rs[TM];
    __shared__ float cs[TM];

    const int tid  = threadIdx.x;
    const int wave = tid >> 6;            // 0..15
    const int lane = tid & 63;
    const int wm   = wave & 3;            // wave row band: rows wm*64..+64
    const int wn   = wave >> 2;           // wave col band: cols wn*64..+64
    const int g    = lane >> 4;           // quad (0..3)
    const int m15  = lane & 15;

    if (tid < TM) { rs[tid] = 0.f; cs[tid] = 0.f; }

    // ---- staging addresses ----
    // wave w stages rows [w*16, w*16+16) of A and B per chunk (1 KB each).
    // lane l -> row w*16+(l>>2), LDS 16B-slot l&3, src slot (l&3)^((l>>3)&3)
    const int st_r0 = wave * 16 + (lane >> 2);
    const int st_c  = (lane & 3) ^ ((lane >> 3) & 3);
    const unsigned char* gA0 = Zb + (size_t)(bi * TM + st_r0) * HDIM + st_c * 16;
    const unsigned char* gB0 = Zb + (size_t)(bj * TM + st_r0) * HDIM + st_c * 16;

    // ---- fragment read offsets ----
    const int xr = (m15 >> 1) & 3;        // storage slot XOR for this row
    const int s0 = g >> 1;                // src slot base within kstep
    const int ha = (g & 1) * 8;           // 8B half within slot
    // byte offsets within a row for kstep 0 / 1:
    const int off0 = ((s0 ^ xr) * 16) + ha;
    const int off1 = (((2 + s0) ^ xr) * 16) + ha;
    const int rowA = (wm * 64 + m15) * BKB;   // + f*16*BKB per frag row
    const int rowB = (wn * 64 + m15) * BKB;

    floatx4 acc[4][4] = {};

    #define STAGE(ck)  do {                                                  \
        const int _o = ((ck) % 3) * 2 * PIECEB;                              \
        async_copy16(gA0 + (ck) * BKB, tiles + _o + (wave * 16) * BKB);      \
        async_copy16(gB0 + (ck) * BKB,                                       \
                     tiles + _o + PIECEB + (wave * 16) * BKB);               \
    } while (0)

    STAGE(0);   // prologue (2 loads in flight entering body 0)

    #pragma unroll
    for (int s = 0; s < NCHUNK; ++s) {
        if (s + 1 < NCHUNK) { STAGE(s + 1); WAIT_VM2(); }
        else                { WAIT_VM0(); }
        RAW_BARRIER();   // all waves' chunk-s loads landed in buf s%3

        const char* bA = tiles + (s % 3) * 2 * PIECEB;
        const char* bB = bA + PIECEB;
        long af[2][4], bfr[2][4];
        #pragma unroll
        for (int ks = 0; ks < 2; ++ks) {
            const int off = ks ? off1 : off0;
            #pragma unroll
            for (int f = 0; f < 4; ++f) {
                af[ks][f]  = *(const long*)(bA + rowA + f * 16 * BKB + off);
                bfr[ks][f] = *(const long*)(bB + rowB + f * 16 * BKB + off);
            }
        }
        __builtin_amdgcn_s_setprio(1);
        #pragma unroll
        for (int ks = 0; ks < 2; ++ks)
            #pragma unroll
            for (int fm = 0; fm < 4; ++fm)
                #pragma unroll
                for (int fn = 0; fn < 4; ++fn)
                    acc[fm][fn] = __builtin_amdgcn_mfma_f32_16x16x32_fp8_fp8(
                        af[ks][fm], bfr[ks][fn], acc[fm][fn], 0, 0, 0);
        __builtin_amdgcn_s_setprio(0);
        // no 2nd barrier / lgkm drain: WAR argument as in R16
    }
    #undef STAGE

    // ---- epilogue: e = exp2(acc) (== exp(sim/tau)), reduce rows & cols ----
    float rp[4][4] = {{0.f}};  // [fm][reg] partial row sums
    float cp[4]    = {0.f};    // [fn]      partial col sums

    if (!diag) {
        #pragma unroll
        for (int fm = 0; fm < 4; ++fm)
            #pragma unroll
            for (int fn = 0; fn < 4; ++fn) {
                const floatx4 a = acc[fm][fn];
                #pragma unroll
                for (int q = 0; q < 4; ++q) {
                    const float e = __builtin_amdgcn_exp2f(a[q]);
                    rp[fm][q] += e;
                    cp[fn]    += e;
                }
            }
    } else {
        #pragma unroll
        for (int fm = 0; fm < 4; ++fm)
            #pragma unroll
            for (int fn = 0; fn < 4; ++fn) {
                const floatx4 a = acc[fm][fn];
                const int cl = wn * 64 + fn * 16 + m15;
                #pragma unroll
                for (int q = 0; q < 4; ++q) {
                    const int rl = wm * 64 + fm * 16 + g * 4 + q;
                    float e = __builtin_amdgcn_exp2f(a[q]);
                    if (cl <= rl) e = 0.f;   // strictly-upper only
                    rp[fm][q] += e;
                    cp[fn]    += e;
                }
            }
    }

    // row sums: 16-lane DPP reduction (VALU pipe); total lands in m15==0
    #pragma unroll
    for (int fm = 0; fm < 4; ++fm)
        #pragma unroll
        for (int q = 0; q < 4; ++q) {
            float v = rp[fm][q];
            DPP_ROW_SHL_ADD(v, 0x101);   // row_shl:1
            DPP_ROW_SHL_ADD(v, 0x102);   // row_shl:2
            DPP_ROW_SHL_ADD(v, 0x104);   // row_shl:4
            DPP_ROW_SHL_ADD(v, 0x108);   // row_shl:8
            rp[fm][q] = v;
        }
    if (m15 == 0) {
        #pragma unroll
        for (int fm = 0; fm < 4; ++fm)
            #pragma unroll
            for (int q = 0; q < 4; ++q)
                atomicAdd(&rs[wm * 64 + fm * 16 + g * 4 + q], rp[fm][q]);
    }

    // col sums: reduce across quads
    #pragma unroll
    for (int mask = 16; mask < 64; mask <<= 1)
        #pragma unroll
        for (int fn = 0; fn < 4; ++fn)
            cp[fn] += __shfl_xor(cp[fn], mask);
    if (g == 0) {
        #pragma unroll
        for (int fn = 0; fn < 4; ++fn)
            atomicAdd(&cs[wn * 64 + fn * 16 + m15], cp[fn]);
    }

    __syncthreads();
    if (tid < TM) {
        atomicAdd(&rowsum[(size_t)bi * TM + tid], rs[tid]);
        atomicAdd(&rowsum[(size_t)bj * TM + tid], cs[tid]);
    }
}

// ---------------------------------------------------------------------------
// Kernel 3: loss = mean( log(rowsum_i) - 2*pos_i ), 16 blocks + atomic.
// ---------------------------------------------------------------------------
__global__ __launch_bounds__(1024) void finalize_kernel(
    const float* __restrict__ rowsum, const float* __restrict__ pos,
    float* __restrict__ out)
{
    const int i = threadIdx.x + blockIdx.x * 1024;
    float s = logf(rowsum[i]) - 2.0f * pos[i];
    #pragma unroll
    for (int off = 32; off; off >>= 1) s += __shfl_down(s, off);
    __shared__ float sh[16];
    const int lt = threadIdx.x;
    if ((lt & 63) == 0) sh[lt >> 6] = s;
    __syncthreads();
    if (lt == 0) {
        float tot = 0.f;
        #pragma unroll
        for (int w = 0; w < 16; ++w) tot += sh[w];
        atomicAdd(out, tot / (float)N2);
    }
}

// ---------------------------------------------------------------------------
extern "C" void kernel_launch(void* const* d_in, const int* in_sizes, int n_in,
                              void* d_out, int out_size, void* d_ws, size_t ws_size,
                              hipStream_t stream)
{
    const float* x = (const float*)d_in[0];
    const float* y = (const float*)d_in[1];

    // workspace: Z fp8 [16384*256] (4 MB) | rowsum f32 [16384] | pos f32 [16384]
    unsigned char* Zb = (unsigned char*)d_ws;
    float* rowsum = (float*)((char*)d_ws + (size_t)N2 * HDIM);
    float* pos    = rowsum + N2;

    normalize_kernel<<<NROWS / 4, 256, 0, stream>>>(x, y, Zb, pos, rowsum, (float*)d_out);
    simgemm_kernel<<<NBLK, 1024, 0, stream>>>(Zb, rowsum);
    finalize_kernel<<<N2 / 1024, 1024, 0, stream>>>(rowsum, pos, (float*)d_out);
}